// Round 6
// baseline (214.826 us; speedup 1.0000x reference)
//
#include <hip/hip_runtime.h>
#include <hip/hip_fp16.h>

// GAT conv: N=100000, E=1.6M, IN_C=128, OUT_C=32, HEADS=4 (OC=128)
// Round 13 (= Round 12 resubmit; bench infra failed, kernel audited clean):
//  - k_tile post-mortem of rounds 9/11: VGPR_Count=28 proved the compiler
//    serialized every "pipelined" gather (512-thr block -> 64-VGPR budget).
//    k_tile now runs 256 threads with __launch_bounds__(256,4) (128-VGPR
//    budget): ingest reads slab into REGISTERS (8 packed/thread, 8 searches
//    + 8 loads in flight, s_packed LDS eliminated -> 28.8 KB), scatter
//    issues all 8 r[col] float4 gathers before any atomic/exp/store, PV is
//    4-deep with fma(w,(float)h,acc) fused cvt+fma (v_fma_mix) halving PV
//    VALU (VALU-issue was 34us, the secondary ceiling).
//  - k_fg unchanged (near streaming floor, ~20us).

constexpr float NEG_SLOPE = 0.2f;
constexpr int TILE_ROWS = 64;       // rows per bucket (row>>6)
constexpr int SLAB = 2048;          // max edges per bucket staged in LDS
constexpr int EPB = 8192;           // edges per fill block
constexpr int NB_PAD = 2048;        // padded bucket count for block scan
constexpr int FBMAX = 256;          // k_tile ingest supports up to 256 fill blocks

typedef __attribute__((ext_vector_type(8))) short short8;
typedef __attribute__((ext_vector_type(4))) float f32x4;

__device__ inline short f2bf(float f) {
    unsigned u = __float_as_uint(f);
    return (short)((u + 0x7fffu + ((u >> 16) & 1u)) >> 16);
}

// Fused fill + gemm, roles interleaved on blockIdx.
__global__ __launch_bounds__(512) void k_fg(const float* __restrict__ x,
                                            const float* __restrict__ W,
                                            const float* __restrict__ attl,
                                            const float* __restrict__ attr,
                                            const int* __restrict__ ei,
                                            __half* __restrict__ xph,
                                            float* __restrict__ l,
                                            float* __restrict__ r,
                                            unsigned int* __restrict__ slab,
                                            int* __restrict__ starts,
                                            int N, int E, int NB, int FB, int S) {
    __shared__ __align__(16) char smem[49152];   // union: fill 48KB / gemm 39.2KB
    __shared__ float s_att[256];                 // attl(128) | attr(128)
    __shared__ int s_wsum[8];
    int t = threadIdx.x;
    int lane = t & 63, wv = t >> 6;
    int b = blockIdx.x;
    bool isfill = (b % S == 0) && (b / S < FB);

    if (isfill) {
        // ------------------------- fill role -------------------------
        int* s_hist = (int*)smem;                       // 8 KB
        int* s_cur  = (int*)(smem + 8192);              // 8 KB
        unsigned int* s_stage = (unsigned int*)(smem + 16384); // 32 KB

        int fb = b / S;
        int e0 = fb * EPB;
        int ecnt = min(EPB, E - e0);
        bool full = (ecnt == EPB) && ((E & 3) == 0);

        for (int i = t; i < NB_PAD; i += 512) s_hist[i] = 0;
        __syncthreads();

        const int* rows = ei;
        const int* cols = ei + E;

        if (full) {
            const int4* r4 = (const int4*)rows + (e0 >> 2);
#pragma unroll
            for (int k = 0; k < 4; ++k) {
                int4 ra = r4[k * 512 + t];
                atomicAdd(&s_hist[ra.x >> 6], 1);
                atomicAdd(&s_hist[ra.y >> 6], 1);
                atomicAdd(&s_hist[ra.z >> 6], 1);
                atomicAdd(&s_hist[ra.w >> 6], 1);
            }
        } else {
            for (int j = t; j < ecnt; j += 512)
                atomicAdd(&s_hist[rows[e0 + j] >> 6], 1);
        }
        __syncthreads();

        int b0 = t * 4;
        int c0 = s_hist[b0], c1 = s_hist[b0 + 1], c2 = s_hist[b0 + 2], c3 = s_hist[b0 + 3];
        int p = c0 + c1 + c2 + c3;
        int v = p;
#pragma unroll
        for (int off = 1; off < 64; off <<= 1) {
            int u = __shfl_up(v, off);
            if (lane >= off) v += u;
        }
        if (lane == 63) s_wsum[wv] = v;
        __syncthreads();
        if (t == 0) {
            int run = 0;
#pragma unroll
            for (int w = 0; w < 8; ++w) { int tmp = s_wsum[w]; s_wsum[w] = run; run += tmp; }
        }
        __syncthreads();
        int base = s_wsum[wv] + (v - p);
        int e1 = base + c0, e2 = e1 + c1, e3 = e2 + c2;
        s_hist[b0] = base; s_hist[b0 + 1] = e1; s_hist[b0 + 2] = e2; s_hist[b0 + 3] = e3;
        s_cur[b0] = base;  s_cur[b0 + 1] = e1;  s_cur[b0 + 2] = e2;  s_cur[b0 + 3] = e3;
        size_t sb = (size_t)fb * (NB + 1);
        if (b0 + 0 <= NB) starts[sb + b0 + 0] = base;
        if (b0 + 1 <= NB) starts[sb + b0 + 1] = e1;
        if (b0 + 2 <= NB) starts[sb + b0 + 2] = e2;
        if (b0 + 3 <= NB) starts[sb + b0 + 3] = e3;
        __syncthreads();

        if (full) {
            const int4* r4 = (const int4*)rows + (e0 >> 2);
            const int4* c4 = (const int4*)cols + (e0 >> 2);
#pragma unroll
            for (int k = 0; k < 4; ++k) {
                int4 ra = r4[k * 512 + t];
                int4 ca = c4[k * 512 + t];
                int pos;
                pos = atomicAdd(&s_cur[ra.x >> 6], 1);
                s_stage[pos] = ((unsigned int)ca.x << 6) | (unsigned int)(ra.x & 63);
                pos = atomicAdd(&s_cur[ra.y >> 6], 1);
                s_stage[pos] = ((unsigned int)ca.y << 6) | (unsigned int)(ra.y & 63);
                pos = atomicAdd(&s_cur[ra.z >> 6], 1);
                s_stage[pos] = ((unsigned int)ca.z << 6) | (unsigned int)(ra.z & 63);
                pos = atomicAdd(&s_cur[ra.w >> 6], 1);
                s_stage[pos] = ((unsigned int)ca.w << 6) | (unsigned int)(ra.w & 63);
            }
        } else {
            for (int j = t; j < ecnt; j += 512) {
                int rr = rows[e0 + j], cc = cols[e0 + j];
                int pos = atomicAdd(&s_cur[rr >> 6], 1);
                s_stage[pos] = ((unsigned int)cc << 6) | (unsigned int)(rr & 63);
            }
        }
        __syncthreads();

        uint4* dst = (uint4*)(slab + (size_t)fb * EPB);
        const uint4* src = (const uint4*)s_stage;
        int n4 = (ecnt + 3) >> 2;
        for (int i = t; i < n4; i += 512) dst[i] = src[i];
        return;
    }

    // ------------------------- gemm role -------------------------
    short* s_wa = (short*)smem;     // 144 rows x 136 shorts (272B stride)
    if (t < 128)       s_att[t] = attl[t];
    else if (t < 256)  s_att[t] = attr[t - 128];
    for (int i = t; i < 128 * 128; i += 512) {
        int row = i >> 7, col = i & 127;
        s_wa[row * 136 + col] = f2bf(W[i]);
    }
    for (int i = t; i < 1024; i += 512) {
        int row = 136 + (i >> 7), col = i & 127;
        s_wa[row * 136 + col] = 0;
    }
    __syncthreads();
#pragma unroll
    for (int s = 0; s < 2; ++s) {
        int e = t + s * 512;                 // 1024 augmented entries
        int which = e >> 9;                  // 0 = l, 1 = r
        int h = (e >> 7) & 3;
        int k = e & 127;
        float acc = 0.f;
#pragma unroll 8
        for (int c = 0; c < 32; ++c)
            acc += s_att[which * 128 + h * 32 + c] * W[(h * 32 + c) * 128 + k];
        s_wa[(128 + which * 4 + h) * 136 + k] = f2bf(acc);
    }
    __syncthreads();

    int li = lane & 15, quad = lane >> 4;
    int gb = b - min((b + S - 1) / S, FB);
    int base = gb * 128 + wv * 16;

    f32x4 acc[9];
#pragma unroll
    for (int nt = 0; nt < 9; ++nt) acc[nt] = (f32x4){0.f, 0.f, 0.f, 0.f};

    int anode = base + li;
    bool avalid = anode < N;
    const float4* x4 = (const float4*)x;
    const short8* wb8 = (const short8*)s_wa;

#pragma unroll
    for (int kc = 0; kc < 4; ++kc) {
        float4 p0 = make_float4(0.f, 0.f, 0.f, 0.f), p1 = p0;
        if (avalid) {
            p0 = x4[(size_t)anode * 32 + kc * 8 + quad * 2];
            p1 = x4[(size_t)anode * 32 + kc * 8 + quad * 2 + 1];
        }
        short8 a;
        a[0] = f2bf(p0.x); a[1] = f2bf(p0.y); a[2] = f2bf(p0.z); a[3] = f2bf(p0.w);
        a[4] = f2bf(p1.x); a[5] = f2bf(p1.y); a[6] = f2bf(p1.z); a[7] = f2bf(p1.w);
#pragma unroll
        for (int nt = 0; nt < 9; ++nt) {
            short8 bfrag = wb8[(nt * 16 + li) * 17 + kc * 4 + quad];
            acc[nt] = __builtin_amdgcn_mfma_f32_16x16x32_bf16(a, bfrag, acc[nt], 0, 0, 0);
        }
    }

#pragma unroll
    for (int j = 0; j < 4; ++j) {
        int node = base + quad * 4 + j;
        if (node >= N) continue;
        if (li < 4)      l[node * 4 + li] = acc[8][j];
        else if (li < 8) r[node * 4 + li - 4] = acc[8][j];
    }

    __syncthreads();
    __half* s_out = (__half*)s_wa;   // [128 nodes][136] halves, stride 272B
#pragma unroll
    for (int j = 0; j < 4; ++j) {
        int nl = wv * 16 + quad * 4 + j;
#pragma unroll
        for (int nt = 0; nt < 8; ++nt)
            s_out[nl * 136 + nt * 16 + li] = __float2half(acc[nt][j]);
    }
    __syncthreads();
    {
        int nl = t >> 2, seg = t & 3;
        int node = gb * 128 + nl;
        if (node < N) {
            const short8* sr = (const short8*)s_wa;
            short8* xp8 = (short8*)xph;
#pragma unroll
            for (int q = 0; q < 4; ++q)
                xp8[(size_t)node * 16 + seg * 4 + q] = sr[nl * 17 + seg * 4 + q];
        }
    }
}

// One block per bucket, 256 threads = 4 waves, 128-VGPR budget.
__global__ __launch_bounds__(256, 4) void k_tile(const int* __restrict__ starts,
                                                 const unsigned int* __restrict__ slab,
                                                 const float* __restrict__ l,
                                                 const float* __restrict__ r,
                                                 const __half* __restrict__ xph,
                                                 const float* __restrict__ bias,
                                                 float* __restrict__ out,
                                                 int N, int NB, int FB) {
    __shared__ int s_col[SLAB];               // 8 KB
    __shared__ __half s_w[SLAB * 4];          // 16 KB: [pos][h]
    __shared__ float s_dsum[TILE_ROWS * 4];   // 1 KB
    __shared__ float s_l[TILE_ROWS * 4];      // 1 KB
    __shared__ int s_start[TILE_ROWS + 1];
    __shared__ int s_cursor[TILE_ROWS];
    __shared__ int s_cnt[TILE_ROWS];
    __shared__ int s_fbase[FBMAX];
    __shared__ int s_foff[FBMAX + 1];
    __shared__ int s_w4[4];

    int b = blockIdx.x;
    int base = b * TILE_ROWS;
    int t = threadIdx.x;
    int lane = t & 63, wv = t >> 6;
    int rows = min(TILE_ROWS, N - base);

    if (t < TILE_ROWS) s_cnt[t] = 0;
    if (t < rows * 4) s_l[t] = l[base * 4 + t];

    // per-fill-block run start/count for this bucket (FB <= 256)
    int myc = 0;
    if (t < FB) {
        const int* sp = starts + (size_t)t * (NB + 1) + b;
        int a0 = sp[0], a1 = sp[1];
        s_fbase[t] = a0;
        myc = a1 - a0;
    }
    int v = myc;
#pragma unroll
    for (int off = 1; off < 64; off <<= 1) {
        int u = __shfl_up(v, off);
        if (lane >= off) v += u;
    }
    if (lane == 63) s_w4[wv] = v;
    __syncthreads();
    if (t == 0) {
        int run = 0;
#pragma unroll
        for (int w = 0; w < 4; ++w) { int tmp = s_w4[w]; s_w4[w] = run; run += tmp; }
        s_foff[0] = 0;
    }
    __syncthreads();
    s_foff[t + 1] = v + s_w4[wv];
    __syncthreads();
    int tot = s_foff[FB];
    if (tot > SLAB) tot = SLAB;

    // ingest into REGISTERS: 8 slots/thread, 8 independent searches + loads
    unsigned int pk[8];
#pragma unroll
    for (int s = 0; s < 8; ++s) {
        int i = t + s * 256;
        pk[s] = 0xFFFFFFFFu;
        if (i < tot) {
            int lo = 0, hi = FB;
            while (hi - lo > 1) {
                int mid = (lo + hi) >> 1;
                if (s_foff[mid] <= i) lo = mid; else hi = mid;
            }
            pk[s] = slab[(size_t)lo * EPB + s_fbase[lo] + (i - s_foff[lo])];
        }
    }
#pragma unroll
    for (int s = 0; s < 8; ++s)
        if (pk[s] != 0xFFFFFFFFu) atomicAdd(&s_cnt[pk[s] & 63], 1);
    __syncthreads();

    // counting-sort prefix per row (single wave)
    if (t < 64) {
        int c = s_cnt[t];
        int vv = c;
#pragma unroll
        for (int off = 1; off < 64; off <<= 1) {
            int u = __shfl_up(vv, off);
            if (t >= off) vv += u;
        }
        s_start[t + 1] = vv;
        if (t == 0) s_start[0] = 0;
        s_cursor[t] = vv - c;
    }
    __syncthreads();

    // scatter + alpha: issue ALL 8 r[col] gathers before any atomic/exp/store
    {
        int row_[8], col_[8];
#pragma unroll
        for (int s = 0; s < 8; ++s) {
            row_[s] = (int)(pk[s] & 63);
            col_[s] = (pk[s] != 0xFFFFFFFFu) ? (int)(pk[s] >> 6) : 0;
        }
        float4 rv[8];
#pragma unroll
        for (int s = 0; s < 8; ++s) rv[s] = ((const float4*)r)[col_[s]];
#pragma unroll
        for (int s = 0; s < 8; ++s) {
            if (pk[s] == 0xFFFFFFFFu) continue;
            int row = row_[s];
            int pos = atomicAdd(&s_cursor[row], 1);
            s_col[pos] = col_[s];
            float4 lv = ((const float4*)s_l)[row];
            float w0 = lv.x + rv[s].x, w1 = lv.y + rv[s].y;
            float w2 = lv.z + rv[s].z, w3 = lv.w + rv[s].w;
            w0 = w0 >= 0.f ? w0 : NEG_SLOPE * w0;
            w1 = w1 >= 0.f ? w1 : NEG_SLOPE * w1;
            w2 = w2 >= 0.f ? w2 : NEG_SLOPE * w2;
            w3 = w3 >= 0.f ? w3 : NEG_SLOPE * w3;
            w0 = __expf(w0); w1 = __expf(w1); w2 = __expf(w2); w3 = __expf(w3);
            ((__half2*)s_w)[pos * 2]     = __floats2half2_rn(w0, w1);
            ((__half2*)s_w)[pos * 2 + 1] = __floats2half2_rn(w2, w3);
        }
    }
    __syncthreads();

    // atomic-free denominators: thread = (row, head)
    {
        int row = t >> 2, h = t & 3;
        if (row < rows) {
            int s0 = s_start[row], s1 = s_start[row + 1];
            float d = 0.f;
            for (int i = s0; i < s1; ++i)
                d += __half2float(s_w[i * 4 + h]);
            s_dsum[t] = d;
        }
    }
    __syncthreads();

    int quarter = lane >> 4;   // edge slot within wave
    int li = lane & 15;        // channel block: fp16 chans 8li..8li+7
    int h = li >> 2;           // head of this channel block
    const float4* xp4g = (const float4*)xph;  // 16B = 8 halves

    float4 b0 = ((const float4*)bias)[2 * li];
    float4 b1 = ((const float4*)bias)[2 * li + 1];

    for (int rl = wv; rl < rows; rl += 4) {
        int s0 = s_start[rl], s1 = s_start[rl + 1];
        float a0 = 0.f, a1 = 0.f, a2 = 0.f, a3 = 0.f;
        float a4 = 0.f, a5 = 0.f, a6 = 0.f, a7 = 0.f;
        // 4-deep pipelined gather (VGPR budget now allows it in the ISA)
        for (int i0 = s0 + quarter; i0 < s1; i0 += 16) {
            int i1 = i0 + 4, i2 = i0 + 8, i3 = i0 + 12;
            bool v1 = i1 < s1, v2 = i2 < s1, v3 = i3 < s1;
            int c0 = s_col[i0];
            int c1 = v1 ? s_col[i1] : c0;
            int c2 = v2 ? s_col[i2] : c0;
            int c3 = v3 ? s_col[i3] : c0;
            float w0 = __half2float(s_w[i0 * 4 + h]);
            float w1 = v1 ? __half2float(s_w[i1 * 4 + h]) : 0.f;
            float w2 = v2 ? __half2float(s_w[i2 * 4 + h]) : 0.f;
            float w3 = v3 ? __half2float(s_w[i3 * 4 + h]) : 0.f;
            float4 r0 = xp4g[(size_t)c0 * 16 + li];
            float4 r1 = xp4g[(size_t)c1 * 16 + li];
            float4 r2 = xp4g[(size_t)c2 * 16 + li];
            float4 r3 = xp4g[(size_t)c3 * 16 + li];
            // fused cvt+fma (v_fma_mix): acc = fma(w, (float)h, acc)
#define ACC8(raw, w)                                             \
            {                                                    \
                const __half* hp = (const __half*)&(raw);        \
                a0 = fmaf((w), __half2float(hp[0]), a0);         \
                a1 = fmaf((w), __half2float(hp[1]), a1);         \
                a2 = fmaf((w), __half2float(hp[2]), a2);         \
                a3 = fmaf((w), __half2float(hp[3]), a3);         \
                a4 = fmaf((w), __half2float(hp[4]), a4);         \
                a5 = fmaf((w), __half2float(hp[5]), a5);         \
                a6 = fmaf((w), __half2float(hp[6]), a6);         \
                a7 = fmaf((w), __half2float(hp[7]), a7);         \
            }
            ACC8(r0, w0);
            ACC8(r1, w1);
            ACC8(r2, w2);
            ACC8(r3, w3);
#undef ACC8
        }
        a0 += __shfl_xor(a0, 16); a0 += __shfl_xor(a0, 32);
        a1 += __shfl_xor(a1, 16); a1 += __shfl_xor(a1, 32);
        a2 += __shfl_xor(a2, 16); a2 += __shfl_xor(a2, 32);
        a3 += __shfl_xor(a3, 16); a3 += __shfl_xor(a3, 32);
        a4 += __shfl_xor(a4, 16); a4 += __shfl_xor(a4, 32);
        a5 += __shfl_xor(a5, 16); a5 += __shfl_xor(a5, 32);
        a6 += __shfl_xor(a6, 16); a6 += __shfl_xor(a6, 32);
        a7 += __shfl_xor(a7, 16); a7 += __shfl_xor(a7, 32);
        if (quarter == 0) {
            float inv = 1.f / (s_dsum[rl * 4 + h] + 1e-16f);
            float4 o0, o1;
            o0.x = a0 * inv + b0.x; o0.y = a1 * inv + b0.y;
            o0.z = a2 * inv + b0.z; o0.w = a3 * inv + b0.w;
            o1.x = a4 * inv + b1.x; o1.y = a5 * inv + b1.y;
            o1.z = a6 * inv + b1.z; o1.w = a7 * inv + b1.w;
            ((float4*)out)[(size_t)(base + rl) * 32 + 2 * li] = o0;
            ((float4*)out)[(size_t)(base + rl) * 32 + 2 * li + 1] = o1;
        }
    }
}

extern "C" void kernel_launch(void* const* d_in, const int* in_sizes, int n_in,
                              void* d_out, int out_size, void* d_ws, size_t ws_size,
                              hipStream_t stream) {
    const float* x    = (const float*)d_in[0];
    const int*   ei   = (const int*)d_in[1];
    const float* W    = (const float*)d_in[2];
    const float* attl = (const float*)d_in[3];
    const float* attr = (const float*)d_in[4];
    const float* bias = (const float*)d_in[5];
    int N = in_sizes[0] / 128;
    int E = in_sizes[1] / 2;
    int NB = (N + TILE_ROWS - 1) / TILE_ROWS;
    int FB = (E + EPB - 1) / EPB;    // 196 for E=1.6M (k_tile supports <= FBMAX)

    char* ws = (char*)d_ws;
    __half* xph = (__half*)ws;   ws += (size_t)N * 128 * 2;          // 25.6 MB
    float* l    = (float*)ws;    ws += (size_t)N * 4 * 4;
    float* r    = (float*)ws;    ws += (size_t)N * 4 * 4;
    int* starts = (int*)ws;      ws += (size_t)FB * (NB + 1) * 4;    // 1.23 MB
    unsigned int* slab = (unsigned int*)ws; ws += (size_t)FB * EPB * 4; // 6.42 MB

    float* out = (float*)d_out;
    int GB = (N + 127) / 128;
    int TOT = FB + GB;
    int S = TOT / FB; if (S < 1) S = 1;   // fill role every S-th block

    k_fg<<<TOT, 512, 0, stream>>>(x, W, attl, attr, ei, xph, l, r, slab, starts,
                                  N, E, NB, FB, S);
    k_tile<<<NB, 256, 0, stream>>>(starts, slab, l, r, xph, bias, out, N, NB, FB);
}

// Round 7
// 206.651 us; speedup vs baseline: 1.0396x; 1.0396x over previous
//
#include <hip/hip_runtime.h>
#include <hip/hip_fp16.h>

// GAT conv: N=100000, E=1.6M, IN_C=128, OUT_C=32, HEADS=4 (OC=128)
// Round 14:
//  - k_tile: merge the two proven halves. Round 10 (512thr) had waves but
//    28 VGPR -> serialized gathers; round 13 (256thr) had a real 4-deep
//    pipeline (44 VGPR) but occupancy fell 60%->36% and dur got WORSE.
//    Gather throughput tracks waves x depth (fabric-latency-bound PV).
//    Now: 512 threads + __launch_bounds__(512,8) (VGPR<=64, fits the
//    44-reg pipeline) + register ingest (4 slots/thread) + batched
//    4-gather scatter + 4-deep PV. LDS 28.9KB -> 4 blocks/CU -> 32-wave
//    cap. In-flight lines/CU ~2.4x either previous round.
//  - k_fg unchanged.

constexpr float NEG_SLOPE = 0.2f;
constexpr int TILE_ROWS = 64;       // rows per bucket (row>>6)
constexpr int SLAB = 2048;          // max edges per bucket staged in LDS
constexpr int EPB = 8192;           // edges per fill block
constexpr int NB_PAD = 2048;        // padded bucket count for block scan
constexpr int FBMAX = 256;          // k_tile ingest supports up to 256 fill blocks

typedef __attribute__((ext_vector_type(8))) short short8;
typedef __attribute__((ext_vector_type(4))) float f32x4;

__device__ inline short f2bf(float f) {
    unsigned u = __float_as_uint(f);
    return (short)((u + 0x7fffu + ((u >> 16) & 1u)) >> 16);
}

// Fused fill + gemm, roles interleaved on blockIdx.
__global__ __launch_bounds__(512) void k_fg(const float* __restrict__ x,
                                            const float* __restrict__ W,
                                            const float* __restrict__ attl,
                                            const float* __restrict__ attr,
                                            const int* __restrict__ ei,
                                            __half* __restrict__ xph,
                                            float* __restrict__ l,
                                            float* __restrict__ r,
                                            unsigned int* __restrict__ slab,
                                            int* __restrict__ starts,
                                            int N, int E, int NB, int FB, int S) {
    __shared__ __align__(16) char smem[49152];   // union: fill 48KB / gemm 39.2KB
    __shared__ float s_att[256];                 // attl(128) | attr(128)
    __shared__ int s_wsum[8];
    int t = threadIdx.x;
    int lane = t & 63, wv = t >> 6;
    int b = blockIdx.x;
    bool isfill = (b % S == 0) && (b / S < FB);

    if (isfill) {
        // ------------------------- fill role -------------------------
        int* s_hist = (int*)smem;                       // 8 KB
        int* s_cur  = (int*)(smem + 8192);              // 8 KB
        unsigned int* s_stage = (unsigned int*)(smem + 16384); // 32 KB

        int fb = b / S;
        int e0 = fb * EPB;
        int ecnt = min(EPB, E - e0);
        bool full = (ecnt == EPB) && ((E & 3) == 0);

        for (int i = t; i < NB_PAD; i += 512) s_hist[i] = 0;
        __syncthreads();

        const int* rows = ei;
        const int* cols = ei + E;

        if (full) {
            const int4* r4 = (const int4*)rows + (e0 >> 2);
#pragma unroll
            for (int k = 0; k < 4; ++k) {
                int4 ra = r4[k * 512 + t];
                atomicAdd(&s_hist[ra.x >> 6], 1);
                atomicAdd(&s_hist[ra.y >> 6], 1);
                atomicAdd(&s_hist[ra.z >> 6], 1);
                atomicAdd(&s_hist[ra.w >> 6], 1);
            }
        } else {
            for (int j = t; j < ecnt; j += 512)
                atomicAdd(&s_hist[rows[e0 + j] >> 6], 1);
        }
        __syncthreads();

        int b0 = t * 4;
        int c0 = s_hist[b0], c1 = s_hist[b0 + 1], c2 = s_hist[b0 + 2], c3 = s_hist[b0 + 3];
        int p = c0 + c1 + c2 + c3;
        int v = p;
#pragma unroll
        for (int off = 1; off < 64; off <<= 1) {
            int u = __shfl_up(v, off);
            if (lane >= off) v += u;
        }
        if (lane == 63) s_wsum[wv] = v;
        __syncthreads();
        if (t == 0) {
            int run = 0;
#pragma unroll
            for (int w = 0; w < 8; ++w) { int tmp = s_wsum[w]; s_wsum[w] = run; run += tmp; }
        }
        __syncthreads();
        int base = s_wsum[wv] + (v - p);
        int e1 = base + c0, e2 = e1 + c1, e3 = e2 + c2;
        s_hist[b0] = base; s_hist[b0 + 1] = e1; s_hist[b0 + 2] = e2; s_hist[b0 + 3] = e3;
        s_cur[b0] = base;  s_cur[b0 + 1] = e1;  s_cur[b0 + 2] = e2;  s_cur[b0 + 3] = e3;
        size_t sb = (size_t)fb * (NB + 1);
        if (b0 + 0 <= NB) starts[sb + b0 + 0] = base;
        if (b0 + 1 <= NB) starts[sb + b0 + 1] = e1;
        if (b0 + 2 <= NB) starts[sb + b0 + 2] = e2;
        if (b0 + 3 <= NB) starts[sb + b0 + 3] = e3;
        __syncthreads();

        if (full) {
            const int4* r4 = (const int4*)rows + (e0 >> 2);
            const int4* c4 = (const int4*)cols + (e0 >> 2);
#pragma unroll
            for (int k = 0; k < 4; ++k) {
                int4 ra = r4[k * 512 + t];
                int4 ca = c4[k * 512 + t];
                int pos;
                pos = atomicAdd(&s_cur[ra.x >> 6], 1);
                s_stage[pos] = ((unsigned int)ca.x << 6) | (unsigned int)(ra.x & 63);
                pos = atomicAdd(&s_cur[ra.y >> 6], 1);
                s_stage[pos] = ((unsigned int)ca.y << 6) | (unsigned int)(ra.y & 63);
                pos = atomicAdd(&s_cur[ra.z >> 6], 1);
                s_stage[pos] = ((unsigned int)ca.z << 6) | (unsigned int)(ra.z & 63);
                pos = atomicAdd(&s_cur[ra.w >> 6], 1);
                s_stage[pos] = ((unsigned int)ca.w << 6) | (unsigned int)(ra.w & 63);
            }
        } else {
            for (int j = t; j < ecnt; j += 512) {
                int rr = rows[e0 + j], cc = cols[e0 + j];
                int pos = atomicAdd(&s_cur[rr >> 6], 1);
                s_stage[pos] = ((unsigned int)cc << 6) | (unsigned int)(rr & 63);
            }
        }
        __syncthreads();

        uint4* dst = (uint4*)(slab + (size_t)fb * EPB);
        const uint4* src = (const uint4*)s_stage;
        int n4 = (ecnt + 3) >> 2;
        for (int i = t; i < n4; i += 512) dst[i] = src[i];
        return;
    }

    // ------------------------- gemm role -------------------------
    short* s_wa = (short*)smem;     // 144 rows x 136 shorts (272B stride)
    if (t < 128)       s_att[t] = attl[t];
    else if (t < 256)  s_att[t] = attr[t - 128];
    for (int i = t; i < 128 * 128; i += 512) {
        int row = i >> 7, col = i & 127;
        s_wa[row * 136 + col] = f2bf(W[i]);
    }
    for (int i = t; i < 1024; i += 512) {
        int row = 136 + (i >> 7), col = i & 127;
        s_wa[row * 136 + col] = 0;
    }
    __syncthreads();
#pragma unroll
    for (int s = 0; s < 2; ++s) {
        int e = t + s * 512;                 // 1024 augmented entries
        int which = e >> 9;                  // 0 = l, 1 = r
        int h = (e >> 7) & 3;
        int k = e & 127;
        float acc = 0.f;
#pragma unroll 8
        for (int c = 0; c < 32; ++c)
            acc += s_att[which * 128 + h * 32 + c] * W[(h * 32 + c) * 128 + k];
        s_wa[(128 + which * 4 + h) * 136 + k] = f2bf(acc);
    }
    __syncthreads();

    int li = lane & 15, quad = lane >> 4;
    int gb = b - min((b + S - 1) / S, FB);
    int base = gb * 128 + wv * 16;

    f32x4 acc[9];
#pragma unroll
    for (int nt = 0; nt < 9; ++nt) acc[nt] = (f32x4){0.f, 0.f, 0.f, 0.f};

    int anode = base + li;
    bool avalid = anode < N;
    const float4* x4 = (const float4*)x;
    const short8* wb8 = (const short8*)s_wa;

#pragma unroll
    for (int kc = 0; kc < 4; ++kc) {
        float4 p0 = make_float4(0.f, 0.f, 0.f, 0.f), p1 = p0;
        if (avalid) {
            p0 = x4[(size_t)anode * 32 + kc * 8 + quad * 2];
            p1 = x4[(size_t)anode * 32 + kc * 8 + quad * 2 + 1];
        }
        short8 a;
        a[0] = f2bf(p0.x); a[1] = f2bf(p0.y); a[2] = f2bf(p0.z); a[3] = f2bf(p0.w);
        a[4] = f2bf(p1.x); a[5] = f2bf(p1.y); a[6] = f2bf(p1.z); a[7] = f2bf(p1.w);
#pragma unroll
        for (int nt = 0; nt < 9; ++nt) {
            short8 bfrag = wb8[(nt * 16 + li) * 17 + kc * 4 + quad];
            acc[nt] = __builtin_amdgcn_mfma_f32_16x16x32_bf16(a, bfrag, acc[nt], 0, 0, 0);
        }
    }

#pragma unroll
    for (int j = 0; j < 4; ++j) {
        int node = base + quad * 4 + j;
        if (node >= N) continue;
        if (li < 4)      l[node * 4 + li] = acc[8][j];
        else if (li < 8) r[node * 4 + li - 4] = acc[8][j];
    }

    __syncthreads();
    __half* s_out = (__half*)s_wa;   // [128 nodes][136] halves, stride 272B
#pragma unroll
    for (int j = 0; j < 4; ++j) {
        int nl = wv * 16 + quad * 4 + j;
#pragma unroll
        for (int nt = 0; nt < 8; ++nt)
            s_out[nl * 136 + nt * 16 + li] = __float2half(acc[nt][j]);
    }
    __syncthreads();
    {
        int nl = t >> 2, seg = t & 3;
        int node = gb * 128 + nl;
        if (node < N) {
            const short8* sr = (const short8*)s_wa;
            short8* xp8 = (short8*)xph;
#pragma unroll
            for (int q = 0; q < 4; ++q)
                xp8[(size_t)node * 16 + seg * 4 + q] = sr[nl * 17 + seg * 4 + q];
        }
    }
}

// One block per bucket, 512 threads = 8 waves, VGPR<=64 (8 waves/EU floor).
__global__ __launch_bounds__(512, 8) void k_tile(const int* __restrict__ starts,
                                                 const unsigned int* __restrict__ slab,
                                                 const float* __restrict__ l,
                                                 const float* __restrict__ r,
                                                 const __half* __restrict__ xph,
                                                 const float* __restrict__ bias,
                                                 float* __restrict__ out,
                                                 int N, int NB, int FB) {
    __shared__ int s_col[SLAB];               // 8 KB
    __shared__ __half s_w[SLAB * 4];          // 16 KB: [pos][h]
    __shared__ float s_dsum[TILE_ROWS * 4];   // 1 KB
    __shared__ float s_l[TILE_ROWS * 4];      // 1 KB
    __shared__ int s_start[TILE_ROWS + 1];
    __shared__ int s_cursor[TILE_ROWS];
    __shared__ int s_cnt[TILE_ROWS];
    __shared__ int s_fbase[FBMAX];
    __shared__ int s_foff[FBMAX + 1];
    __shared__ int s_w4[4];

    int b = blockIdx.x;
    int base = b * TILE_ROWS;
    int t = threadIdx.x;
    int lane = t & 63, wv = t >> 6;
    int rows = min(TILE_ROWS, N - base);

    if (t < TILE_ROWS) s_cnt[t] = 0;
    if (t < rows * 4) s_l[t] = l[base * 4 + t];

    // per-fill-block run start/count for this bucket (FB <= 256)
    int myc = 0;
    if (t < FB) {
        const int* sp = starts + (size_t)t * (NB + 1) + b;
        int a0 = sp[0], a1 = sp[1];
        s_fbase[t] = a0;
        myc = a1 - a0;
    }
    if (t < 256) {
        int v = myc;
#pragma unroll
        for (int off = 1; off < 64; off <<= 1) {
            int u = __shfl_up(v, off);
            if (lane >= off) v += u;
        }
        if (lane == 63) s_w4[wv] = v;
        // stash scan result for after the barrier
        s_foff[t + 1] = v;     // provisional (pre wave-offset)
    }
    __syncthreads();
    if (t == 0) {
        int run = 0;
#pragma unroll
        for (int w = 0; w < 4; ++w) { int tmp = s_w4[w]; s_w4[w] = run; run += tmp; }
        s_foff[0] = 0;
    }
    __syncthreads();
    if (t < 256) s_foff[t + 1] += s_w4[wv];
    __syncthreads();
    int tot = s_foff[FB];
    if (tot > SLAB) tot = SLAB;

    // ingest into REGISTERS: 4 slots/thread, 4 independent searches + loads
    unsigned int pk[4];
#pragma unroll
    for (int s = 0; s < 4; ++s) {
        int i = t + s * 512;
        pk[s] = 0xFFFFFFFFu;
        if (i < tot) {
            int lo = 0, hi = FB;
            while (hi - lo > 1) {
                int mid = (lo + hi) >> 1;
                if (s_foff[mid] <= i) lo = mid; else hi = mid;
            }
            pk[s] = slab[(size_t)lo * EPB + s_fbase[lo] + (i - s_foff[lo])];
        }
    }
#pragma unroll
    for (int s = 0; s < 4; ++s)
        if (pk[s] != 0xFFFFFFFFu) atomicAdd(&s_cnt[pk[s] & 63], 1);
    __syncthreads();

    // counting-sort prefix per row (single wave)
    if (t < 64) {
        int c = s_cnt[t];
        int vv = c;
#pragma unroll
        for (int off = 1; off < 64; off <<= 1) {
            int u = __shfl_up(vv, off);
            if (t >= off) vv += u;
        }
        s_start[t + 1] = vv;
        if (t == 0) s_start[0] = 0;
        s_cursor[t] = vv - c;
    }
    __syncthreads();

    // scatter + alpha: issue ALL 4 r[col] gathers before any atomic/exp/store
    {
        int row_[4], col_[4];
#pragma unroll
        for (int s = 0; s < 4; ++s) {
            row_[s] = (int)(pk[s] & 63);
            col_[s] = (pk[s] != 0xFFFFFFFFu) ? (int)(pk[s] >> 6) : 0;
        }
        float4 rv[4];
#pragma unroll
        for (int s = 0; s < 4; ++s) rv[s] = ((const float4*)r)[col_[s]];
#pragma unroll
        for (int s = 0; s < 4; ++s) {
            if (pk[s] == 0xFFFFFFFFu) continue;
            int row = row_[s];
            int pos = atomicAdd(&s_cursor[row], 1);
            s_col[pos] = col_[s];
            float4 lv = ((const float4*)s_l)[row];
            float w0 = lv.x + rv[s].x, w1 = lv.y + rv[s].y;
            float w2 = lv.z + rv[s].z, w3 = lv.w + rv[s].w;
            w0 = w0 >= 0.f ? w0 : NEG_SLOPE * w0;
            w1 = w1 >= 0.f ? w1 : NEG_SLOPE * w1;
            w2 = w2 >= 0.f ? w2 : NEG_SLOPE * w2;
            w3 = w3 >= 0.f ? w3 : NEG_SLOPE * w3;
            w0 = __expf(w0); w1 = __expf(w1); w2 = __expf(w2); w3 = __expf(w3);
            ((__half2*)s_w)[pos * 2]     = __floats2half2_rn(w0, w1);
            ((__half2*)s_w)[pos * 2 + 1] = __floats2half2_rn(w2, w3);
        }
    }
    __syncthreads();

    // atomic-free denominators: thread = (row, head)
    if (t < 256) {
        int row = t >> 2, h = t & 3;
        if (row < rows) {
            int s0 = s_start[row], s1 = s_start[row + 1];
            float d = 0.f;
            for (int i = s0; i < s1; ++i)
                d += __half2float(s_w[i * 4 + h]);
            s_dsum[t] = d;
        }
    }
    __syncthreads();

    int quarter = lane >> 4;   // edge slot within wave
    int li = lane & 15;        // channel block: fp16 chans 8li..8li+7
    int h = li >> 2;           // head of this channel block
    const float4* xp4g = (const float4*)xph;  // 16B = 8 halves

    float4 b0 = ((const float4*)bias)[2 * li];
    float4 b1 = ((const float4*)bias)[2 * li + 1];

    for (int rl = wv; rl < rows; rl += 8) {
        int s0 = s_start[rl], s1 = s_start[rl + 1];
        float a0 = 0.f, a1 = 0.f, a2 = 0.f, a3 = 0.f;
        float a4 = 0.f, a5 = 0.f, a6 = 0.f, a7 = 0.f;
        // 4-deep pipelined gather
        for (int i0 = s0 + quarter; i0 < s1; i0 += 16) {
            int i1 = i0 + 4, i2 = i0 + 8, i3 = i0 + 12;
            bool v1 = i1 < s1, v2 = i2 < s1, v3 = i3 < s1;
            int c0 = s_col[i0];
            int c1 = v1 ? s_col[i1] : c0;
            int c2 = v2 ? s_col[i2] : c0;
            int c3 = v3 ? s_col[i3] : c0;
            float w0 = __half2float(s_w[i0 * 4 + h]);
            float w1 = v1 ? __half2float(s_w[i1 * 4 + h]) : 0.f;
            float w2 = v2 ? __half2float(s_w[i2 * 4 + h]) : 0.f;
            float w3 = v3 ? __half2float(s_w[i3 * 4 + h]) : 0.f;
            float4 r0 = xp4g[(size_t)c0 * 16 + li];
            float4 r1 = xp4g[(size_t)c1 * 16 + li];
            float4 r2 = xp4g[(size_t)c2 * 16 + li];
            float4 r3 = xp4g[(size_t)c3 * 16 + li];
            // fused cvt+fma (v_fma_mix): acc = fma(w, (float)h, acc)
#define ACC8(raw, w)                                             \
            {                                                    \
                const __half* hp = (const __half*)&(raw);        \
                a0 = fmaf((w), __half2float(hp[0]), a0);         \
                a1 = fmaf((w), __half2float(hp[1]), a1);         \
                a2 = fmaf((w), __half2float(hp[2]), a2);         \
                a3 = fmaf((w), __half2float(hp[3]), a3);         \
                a4 = fmaf((w), __half2float(hp[4]), a4);         \
                a5 = fmaf((w), __half2float(hp[5]), a5);         \
                a6 = fmaf((w), __half2float(hp[6]), a6);         \
                a7 = fmaf((w), __half2float(hp[7]), a7);         \
            }
            ACC8(r0, w0);
            ACC8(r1, w1);
            ACC8(r2, w2);
            ACC8(r3, w3);
#undef ACC8
        }
        a0 += __shfl_xor(a0, 16); a0 += __shfl_xor(a0, 32);
        a1 += __shfl_xor(a1, 16); a1 += __shfl_xor(a1, 32);
        a2 += __shfl_xor(a2, 16); a2 += __shfl_xor(a2, 32);
        a3 += __shfl_xor(a3, 16); a3 += __shfl_xor(a3, 32);
        a4 += __shfl_xor(a4, 16); a4 += __shfl_xor(a4, 32);
        a5 += __shfl_xor(a5, 16); a5 += __shfl_xor(a5, 32);
        a6 += __shfl_xor(a6, 16); a6 += __shfl_xor(a6, 32);
        a7 += __shfl_xor(a7, 16); a7 += __shfl_xor(a7, 32);
        if (quarter == 0) {
            float inv = 1.f / (s_dsum[rl * 4 + h] + 1e-16f);
            float4 o0, o1;
            o0.x = a0 * inv + b0.x; o0.y = a1 * inv + b0.y;
            o0.z = a2 * inv + b0.z; o0.w = a3 * inv + b0.w;
            o1.x = a4 * inv + b1.x; o1.y = a5 * inv + b1.y;
            o1.z = a6 * inv + b1.z; o1.w = a7 * inv + b1.w;
            ((float4*)out)[(size_t)(base + rl) * 32 + 2 * li] = o0;
            ((float4*)out)[(size_t)(base + rl) * 32 + 2 * li + 1] = o1;
        }
    }
}

extern "C" void kernel_launch(void* const* d_in, const int* in_sizes, int n_in,
                              void* d_out, int out_size, void* d_ws, size_t ws_size,
                              hipStream_t stream) {
    const float* x    = (const float*)d_in[0];
    const int*   ei   = (const int*)d_in[1];
    const float* W    = (const float*)d_in[2];
    const float* attl = (const float*)d_in[3];
    const float* attr = (const float*)d_in[4];
    const float* bias = (const float*)d_in[5];
    int N = in_sizes[0] / 128;
    int E = in_sizes[1] / 2;
    int NB = (N + TILE_ROWS - 1) / TILE_ROWS;
    int FB = (E + EPB - 1) / EPB;    // 196 for E=1.6M (k_tile supports <= FBMAX)

    char* ws = (char*)d_ws;
    __half* xph = (__half*)ws;   ws += (size_t)N * 128 * 2;          // 25.6 MB
    float* l    = (float*)ws;    ws += (size_t)N * 4 * 4;
    float* r    = (float*)ws;    ws += (size_t)N * 4 * 4;
    int* starts = (int*)ws;      ws += (size_t)FB * (NB + 1) * 4;    // 1.23 MB
    unsigned int* slab = (unsigned int*)ws; ws += (size_t)FB * EPB * 4; // 6.42 MB

    float* out = (float*)d_out;
    int GB = (N + 127) / 128;
    int TOT = FB + GB;
    int S = TOT / FB; if (S < 1) S = 1;   // fill role every S-th block

    k_fg<<<TOT, 512, 0, stream>>>(x, W, attl, attr, ei, xph, l, r, slab, starts,
                                  N, E, NB, FB, S);
    k_tile<<<NB, 512, 0, stream>>>(starts, slab, l, r, xph, bias, out, N, NB, FB);
}

// Round 8
// 205.912 us; speedup vs baseline: 1.0433x; 1.0036x over previous
//
#include <hip/hip_runtime.h>
#include <hip/hip_fp16.h>

// GAT conv: N=100000, E=1.6M, IN_C=128, OUT_C=32, HEADS=4 (OC=128)
// Round 15:
//  - k_tile: branchless 4-deep PV. R14 post-mortem: compiler allocated 28
//    VGPR under the 64-budget because the select chains (v1?s_col[i1]:c0)
//    spike peak pressure past 64 at the load cluster -> loads serialized.
//    Fix: pad every row's edge segment to a multiple of 16 (pad: col=0,
//    w=0 -> gather node0 x 0.0), making all 4 depth slots unconditional.
//    SLAB 2048->1536 (bucket max ~ mu+5sigma=1184; clamp kept) so padded
//    capacity 2560 keeps LDS at 35.6KB -> 4 blocks/CU. Ingest 3 slots/thr.
//    #pragma unroll 1 pins the body. Target: occupancy ~58% AND real
//    depth-4 = ~110 lines in flight/CU (was ~45 in R10/R13/R14, all ~81us).
//  - k_fg unchanged.

constexpr float NEG_SLOPE = 0.2f;
constexpr int TILE_ROWS = 64;       // rows per bucket (row>>6)
constexpr int SLAB = 1536;          // ingest clamp (mean 1024, max ~1184)
constexpr int SLAB_P = 2560;        // padded capacity (1536 + 64*15 = 2496)
constexpr int EPB = 8192;           // edges per fill block
constexpr int NB_PAD = 2048;        // padded bucket count for block scan
constexpr int FBMAX = 256;          // k_tile ingest supports up to 256 fill blocks

typedef __attribute__((ext_vector_type(8))) short short8;
typedef __attribute__((ext_vector_type(4))) float f32x4;

__device__ inline short f2bf(float f) {
    unsigned u = __float_as_uint(f);
    return (short)((u + 0x7fffu + ((u >> 16) & 1u)) >> 16);
}

// Fused fill + gemm, roles interleaved on blockIdx.
__global__ __launch_bounds__(512) void k_fg(const float* __restrict__ x,
                                            const float* __restrict__ W,
                                            const float* __restrict__ attl,
                                            const float* __restrict__ attr,
                                            const int* __restrict__ ei,
                                            __half* __restrict__ xph,
                                            float* __restrict__ l,
                                            float* __restrict__ r,
                                            unsigned int* __restrict__ slab,
                                            int* __restrict__ starts,
                                            int N, int E, int NB, int FB, int S) {
    __shared__ __align__(16) char smem[49152];   // union: fill 48KB / gemm 39.2KB
    __shared__ float s_att[256];                 // attl(128) | attr(128)
    __shared__ int s_wsum[8];
    int t = threadIdx.x;
    int lane = t & 63, wv = t >> 6;
    int b = blockIdx.x;
    bool isfill = (b % S == 0) && (b / S < FB);

    if (isfill) {
        // ------------------------- fill role -------------------------
        int* s_hist = (int*)smem;                       // 8 KB
        int* s_cur  = (int*)(smem + 8192);              // 8 KB
        unsigned int* s_stage = (unsigned int*)(smem + 16384); // 32 KB

        int fb = b / S;
        int e0 = fb * EPB;
        int ecnt = min(EPB, E - e0);
        bool full = (ecnt == EPB) && ((E & 3) == 0);

        for (int i = t; i < NB_PAD; i += 512) s_hist[i] = 0;
        __syncthreads();

        const int* rows = ei;
        const int* cols = ei + E;

        if (full) {
            const int4* r4 = (const int4*)rows + (e0 >> 2);
#pragma unroll
            for (int k = 0; k < 4; ++k) {
                int4 ra = r4[k * 512 + t];
                atomicAdd(&s_hist[ra.x >> 6], 1);
                atomicAdd(&s_hist[ra.y >> 6], 1);
                atomicAdd(&s_hist[ra.z >> 6], 1);
                atomicAdd(&s_hist[ra.w >> 6], 1);
            }
        } else {
            for (int j = t; j < ecnt; j += 512)
                atomicAdd(&s_hist[rows[e0 + j] >> 6], 1);
        }
        __syncthreads();

        int b0 = t * 4;
        int c0 = s_hist[b0], c1 = s_hist[b0 + 1], c2 = s_hist[b0 + 2], c3 = s_hist[b0 + 3];
        int p = c0 + c1 + c2 + c3;
        int v = p;
#pragma unroll
        for (int off = 1; off < 64; off <<= 1) {
            int u = __shfl_up(v, off);
            if (lane >= off) v += u;
        }
        if (lane == 63) s_wsum[wv] = v;
        __syncthreads();
        if (t == 0) {
            int run = 0;
#pragma unroll
            for (int w = 0; w < 8; ++w) { int tmp = s_wsum[w]; s_wsum[w] = run; run += tmp; }
        }
        __syncthreads();
        int base = s_wsum[wv] + (v - p);
        int e1 = base + c0, e2 = e1 + c1, e3 = e2 + c2;
        s_hist[b0] = base; s_hist[b0 + 1] = e1; s_hist[b0 + 2] = e2; s_hist[b0 + 3] = e3;
        s_cur[b0] = base;  s_cur[b0 + 1] = e1;  s_cur[b0 + 2] = e2;  s_cur[b0 + 3] = e3;
        size_t sb = (size_t)fb * (NB + 1);
        if (b0 + 0 <= NB) starts[sb + b0 + 0] = base;
        if (b0 + 1 <= NB) starts[sb + b0 + 1] = e1;
        if (b0 + 2 <= NB) starts[sb + b0 + 2] = e2;
        if (b0 + 3 <= NB) starts[sb + b0 + 3] = e3;
        __syncthreads();

        if (full) {
            const int4* r4 = (const int4*)rows + (e0 >> 2);
            const int4* c4 = (const int4*)cols + (e0 >> 2);
#pragma unroll
            for (int k = 0; k < 4; ++k) {
                int4 ra = r4[k * 512 + t];
                int4 ca = c4[k * 512 + t];
                int pos;
                pos = atomicAdd(&s_cur[ra.x >> 6], 1);
                s_stage[pos] = ((unsigned int)ca.x << 6) | (unsigned int)(ra.x & 63);
                pos = atomicAdd(&s_cur[ra.y >> 6], 1);
                s_stage[pos] = ((unsigned int)ca.y << 6) | (unsigned int)(ra.y & 63);
                pos = atomicAdd(&s_cur[ra.z >> 6], 1);
                s_stage[pos] = ((unsigned int)ca.z << 6) | (unsigned int)(ra.z & 63);
                pos = atomicAdd(&s_cur[ra.w >> 6], 1);
                s_stage[pos] = ((unsigned int)ca.w << 6) | (unsigned int)(ra.w & 63);
            }
        } else {
            for (int j = t; j < ecnt; j += 512) {
                int rr = rows[e0 + j], cc = cols[e0 + j];
                int pos = atomicAdd(&s_cur[rr >> 6], 1);
                s_stage[pos] = ((unsigned int)cc << 6) | (unsigned int)(rr & 63);
            }
        }
        __syncthreads();

        uint4* dst = (uint4*)(slab + (size_t)fb * EPB);
        const uint4* src = (const uint4*)s_stage;
        int n4 = (ecnt + 3) >> 2;
        for (int i = t; i < n4; i += 512) dst[i] = src[i];
        return;
    }

    // ------------------------- gemm role -------------------------
    short* s_wa = (short*)smem;     // 144 rows x 136 shorts (272B stride)
    if (t < 128)       s_att[t] = attl[t];
    else if (t < 256)  s_att[t] = attr[t - 128];
    for (int i = t; i < 128 * 128; i += 512) {
        int row = i >> 7, col = i & 127;
        s_wa[row * 136 + col] = f2bf(W[i]);
    }
    for (int i = t; i < 1024; i += 512) {
        int row = 136 + (i >> 7), col = i & 127;
        s_wa[row * 136 + col] = 0;
    }
    __syncthreads();
#pragma unroll
    for (int s = 0; s < 2; ++s) {
        int e = t + s * 512;                 // 1024 augmented entries
        int which = e >> 9;                  // 0 = l, 1 = r
        int h = (e >> 7) & 3;
        int k = e & 127;
        float acc = 0.f;
#pragma unroll 8
        for (int c = 0; c < 32; ++c)
            acc += s_att[which * 128 + h * 32 + c] * W[(h * 32 + c) * 128 + k];
        s_wa[(128 + which * 4 + h) * 136 + k] = f2bf(acc);
    }
    __syncthreads();

    int li = lane & 15, quad = lane >> 4;
    int gb = b - min((b + S - 1) / S, FB);
    int base = gb * 128 + wv * 16;

    f32x4 acc[9];
#pragma unroll
    for (int nt = 0; nt < 9; ++nt) acc[nt] = (f32x4){0.f, 0.f, 0.f, 0.f};

    int anode = base + li;
    bool avalid = anode < N;
    const float4* x4 = (const float4*)x;
    const short8* wb8 = (const short8*)s_wa;

#pragma unroll
    for (int kc = 0; kc < 4; ++kc) {
        float4 p0 = make_float4(0.f, 0.f, 0.f, 0.f), p1 = p0;
        if (avalid) {
            p0 = x4[(size_t)anode * 32 + kc * 8 + quad * 2];
            p1 = x4[(size_t)anode * 32 + kc * 8 + quad * 2 + 1];
        }
        short8 a;
        a[0] = f2bf(p0.x); a[1] = f2bf(p0.y); a[2] = f2bf(p0.z); a[3] = f2bf(p0.w);
        a[4] = f2bf(p1.x); a[5] = f2bf(p1.y); a[6] = f2bf(p1.z); a[7] = f2bf(p1.w);
#pragma unroll
        for (int nt = 0; nt < 9; ++nt) {
            short8 bfrag = wb8[(nt * 16 + li) * 17 + kc * 4 + quad];
            acc[nt] = __builtin_amdgcn_mfma_f32_16x16x32_bf16(a, bfrag, acc[nt], 0, 0, 0);
        }
    }

#pragma unroll
    for (int j = 0; j < 4; ++j) {
        int node = base + quad * 4 + j;
        if (node >= N) continue;
        if (li < 4)      l[node * 4 + li] = acc[8][j];
        else if (li < 8) r[node * 4 + li - 4] = acc[8][j];
    }

    __syncthreads();
    __half* s_out = (__half*)s_wa;   // [128 nodes][136] halves, stride 272B
#pragma unroll
    for (int j = 0; j < 4; ++j) {
        int nl = wv * 16 + quad * 4 + j;
#pragma unroll
        for (int nt = 0; nt < 8; ++nt)
            s_out[nl * 136 + nt * 16 + li] = __float2half(acc[nt][j]);
    }
    __syncthreads();
    {
        int nl = t >> 2, seg = t & 3;
        int node = gb * 128 + nl;
        if (node < N) {
            const short8* sr = (const short8*)s_wa;
            short8* xp8 = (short8*)xph;
#pragma unroll
            for (int q = 0; q < 4; ++q)
                xp8[(size_t)node * 16 + seg * 4 + q] = sr[nl * 17 + seg * 4 + q];
        }
    }
}

// One block per bucket, 512 threads = 8 waves, VGPR<=64 (8 waves/EU floor).
__global__ __launch_bounds__(512, 8) void k_tile(const int* __restrict__ starts,
                                                 const unsigned int* __restrict__ slab,
                                                 const float* __restrict__ l,
                                                 const float* __restrict__ r,
                                                 const __half* __restrict__ xph,
                                                 const float* __restrict__ bias,
                                                 float* __restrict__ out,
                                                 int N, int NB, int FB) {
    __shared__ int s_col[SLAB_P];             // 10 KB
    __shared__ __half s_w[SLAB_P * 4];        // 20 KB: [pos][h]
    __shared__ float s_dsum[TILE_ROWS * 4];   // 1 KB
    __shared__ float s_l[TILE_ROWS * 4];      // 1 KB
    __shared__ int s_start[TILE_ROWS + 1];    // padded starts
    __shared__ int s_cursor[TILE_ROWS];
    __shared__ int s_cnt[TILE_ROWS];
    __shared__ int s_fbase[FBMAX];
    __shared__ int s_foff[FBMAX + 1];
    __shared__ int s_w4[4];

    int b = blockIdx.x;
    int base = b * TILE_ROWS;
    int t = threadIdx.x;
    int lane = t & 63, wv = t >> 6;
    int rows = min(TILE_ROWS, N - base);

    if (t < TILE_ROWS) s_cnt[t] = 0;
    if (t < rows * 4) s_l[t] = l[base * 4 + t];

    // per-fill-block run start/count for this bucket (FB <= 256)
    int myc = 0;
    if (t < FB) {
        const int* sp = starts + (size_t)t * (NB + 1) + b;
        int a0 = sp[0], a1 = sp[1];
        s_fbase[t] = a0;
        myc = a1 - a0;
    }
    if (t < 256) {
        int v = myc;
#pragma unroll
        for (int off = 1; off < 64; off <<= 1) {
            int u = __shfl_up(v, off);
            if (lane >= off) v += u;
        }
        if (lane == 63) s_w4[wv] = v;
        s_foff[t + 1] = v;     // provisional (pre wave-offset)
    }
    __syncthreads();
    if (t == 0) {
        int run = 0;
#pragma unroll
        for (int w = 0; w < 4; ++w) { int tmp = s_w4[w]; s_w4[w] = run; run += tmp; }
        s_foff[0] = 0;
    }
    __syncthreads();
    if (t < 256) s_foff[t + 1] += s_w4[wv];
    __syncthreads();
    int tot = s_foff[FB];
    if (tot > SLAB) tot = SLAB;

    // ingest into REGISTERS: 3 slots/thread (tot <= 1536), independent
    unsigned int pk[3];
#pragma unroll
    for (int s = 0; s < 3; ++s) {
        int i = t + s * 512;
        pk[s] = 0xFFFFFFFFu;
        if (i < tot) {
            int lo = 0, hi = FB;
            while (hi - lo > 1) {
                int mid = (lo + hi) >> 1;
                if (s_foff[mid] <= i) lo = mid; else hi = mid;
            }
            pk[s] = slab[(size_t)lo * EPB + s_fbase[lo] + (i - s_foff[lo])];
        }
    }
    // zero-init col/w so pad slots are (col=0, w=0)
    for (int i = t; i < SLAB_P; i += 512) s_col[i] = 0;
    for (int i = t; i < SLAB_P * 2; i += 512) ((unsigned int*)s_w)[i] = 0u;
#pragma unroll
    for (int s = 0; s < 3; ++s)
        if (pk[s] != 0xFFFFFFFFu) atomicAdd(&s_cnt[pk[s] & 63], 1);
    __syncthreads();

    // counting-sort prefix per row, PADDED to multiple of 16 (single wave)
    if (t < 64) {
        int c = s_cnt[t];
        int pc = (c + 15) & ~15;
        int vv = pc;
#pragma unroll
        for (int off = 1; off < 64; off <<= 1) {
            int u = __shfl_up(vv, off);
            if (t >= off) vv += u;
        }
        s_start[t + 1] = vv;
        if (t == 0) s_start[0] = 0;
        s_cursor[t] = vv - pc;   // padded exclusive start; real edges go first
    }
    __syncthreads();

    // scatter + alpha: issue ALL 3 r[col] gathers before any atomic/exp/store
    {
        int row_[3], col_[3];
#pragma unroll
        for (int s = 0; s < 3; ++s) {
            row_[s] = (int)(pk[s] & 63);
            col_[s] = (pk[s] != 0xFFFFFFFFu) ? (int)(pk[s] >> 6) : 0;
        }
        float4 rv[3];
#pragma unroll
        for (int s = 0; s < 3; ++s) rv[s] = ((const float4*)r)[col_[s]];
#pragma unroll
        for (int s = 0; s < 3; ++s) {
            if (pk[s] == 0xFFFFFFFFu) continue;
            int row = row_[s];
            int pos = atomicAdd(&s_cursor[row], 1);
            s_col[pos] = col_[s];
            float4 lv = ((const float4*)s_l)[row];
            float w0 = lv.x + rv[s].x, w1 = lv.y + rv[s].y;
            float w2 = lv.z + rv[s].z, w3 = lv.w + rv[s].w;
            w0 = w0 >= 0.f ? w0 : NEG_SLOPE * w0;
            w1 = w1 >= 0.f ? w1 : NEG_SLOPE * w1;
            w2 = w2 >= 0.f ? w2 : NEG_SLOPE * w2;
            w3 = w3 >= 0.f ? w3 : NEG_SLOPE * w3;
            w0 = __expf(w0); w1 = __expf(w1); w2 = __expf(w2); w3 = __expf(w3);
            ((__half2*)s_w)[pos * 2]     = __floats2half2_rn(w0, w1);
            ((__half2*)s_w)[pos * 2 + 1] = __floats2half2_rn(w2, w3);
        }
    }
    __syncthreads();

    // atomic-free denominators: thread = (row, head); pads contribute 0
    if (t < 256) {
        int row = t >> 2, h = t & 3;
        if (row < rows) {
            int s0 = s_start[row], s1 = s_start[row + 1];
            float d = 0.f;
            for (int i = s0; i < s1; ++i)
                d += __half2float(s_w[i * 4 + h]);
            s_dsum[t] = d;
        }
    }
    __syncthreads();

    int quarter = lane >> 4;   // edge slot within wave
    int li = lane & 15;        // channel block: fp16 chans 8li..8li+7
    int h = li >> 2;           // head of this channel block
    const float4* xp4g = (const float4*)xph;  // 16B = 8 halves

    float4 b0 = ((const float4*)bias)[2 * li];
    float4 b1 = ((const float4*)bias)[2 * li + 1];

    for (int rl = wv; rl < rows; rl += 8) {
        int s0 = s_start[rl], s1 = s_start[rl + 1];   // padded range, %16 == 0
        float a0 = 0.f, a1 = 0.f, a2 = 0.f, a3 = 0.f;
        float a4 = 0.f, a5 = 0.f, a6 = 0.f, a7 = 0.f;
        // branchless 4-deep pipelined gather: all slots valid (pads w=0)
#pragma unroll 1
        for (int i0 = s0 + quarter; i0 < s1; i0 += 16) {
            int c0 = s_col[i0];
            int c1 = s_col[i0 + 4];
            int c2 = s_col[i0 + 8];
            int c3 = s_col[i0 + 12];
            float w0 = __half2float(s_w[i0 * 4 + h]);
            float w1 = __half2float(s_w[(i0 + 4) * 4 + h]);
            float w2 = __half2float(s_w[(i0 + 8) * 4 + h]);
            float w3 = __half2float(s_w[(i0 + 12) * 4 + h]);
            float4 r0 = xp4g[(size_t)c0 * 16 + li];
            float4 r1 = xp4g[(size_t)c1 * 16 + li];
            float4 r2 = xp4g[(size_t)c2 * 16 + li];
            float4 r3 = xp4g[(size_t)c3 * 16 + li];
            // fused cvt+fma (v_fma_mix): acc = fma(w, (float)h, acc)
#define ACC8(raw, w)                                             \
            {                                                    \
                const __half* hp = (const __half*)&(raw);        \
                a0 = fmaf((w), __half2float(hp[0]), a0);         \
                a1 = fmaf((w), __half2float(hp[1]), a1);         \
                a2 = fmaf((w), __half2float(hp[2]), a2);         \
                a3 = fmaf((w), __half2float(hp[3]), a3);         \
                a4 = fmaf((w), __half2float(hp[4]), a4);         \
                a5 = fmaf((w), __half2float(hp[5]), a5);         \
                a6 = fmaf((w), __half2float(hp[6]), a6);         \
                a7 = fmaf((w), __half2float(hp[7]), a7);         \
            }
            ACC8(r0, w0);
            ACC8(r1, w1);
            ACC8(r2, w2);
            ACC8(r3, w3);
#undef ACC8
        }
        a0 += __shfl_xor(a0, 16); a0 += __shfl_xor(a0, 32);
        a1 += __shfl_xor(a1, 16); a1 += __shfl_xor(a1, 32);
        a2 += __shfl_xor(a2, 16); a2 += __shfl_xor(a2, 32);
        a3 += __shfl_xor(a3, 16); a3 += __shfl_xor(a3, 32);
        a4 += __shfl_xor(a4, 16); a4 += __shfl_xor(a4, 32);
        a5 += __shfl_xor(a5, 16); a5 += __shfl_xor(a5, 32);
        a6 += __shfl_xor(a6, 16); a6 += __shfl_xor(a6, 32);
        a7 += __shfl_xor(a7, 16); a7 += __shfl_xor(a7, 32);
        if (quarter == 0) {
            float inv = 1.f / (s_dsum[rl * 4 + h] + 1e-16f);
            float4 o0, o1;
            o0.x = a0 * inv + b0.x; o0.y = a1 * inv + b0.y;
            o0.z = a2 * inv + b0.z; o0.w = a3 * inv + b0.w;
            o1.x = a4 * inv + b1.x; o1.y = a5 * inv + b1.y;
            o1.z = a6 * inv + b1.z; o1.w = a7 * inv + b1.w;
            ((float4*)out)[(size_t)(base + rl) * 32 + 2 * li] = o0;
            ((float4*)out)[(size_t)(base + rl) * 32 + 2 * li + 1] = o1;
        }
    }
}

extern "C" void kernel_launch(void* const* d_in, const int* in_sizes, int n_in,
                              void* d_out, int out_size, void* d_ws, size_t ws_size,
                              hipStream_t stream) {
    const float* x    = (const float*)d_in[0];
    const int*   ei   = (const int*)d_in[1];
    const float* W    = (const float*)d_in[2];
    const float* attl = (const float*)d_in[3];
    const float* attr = (const float*)d_in[4];
    const float* bias = (const float*)d_in[5];
    int N = in_sizes[0] / 128;
    int E = in_sizes[1] / 2;
    int NB = (N + TILE_ROWS - 1) / TILE_ROWS;
    int FB = (E + EPB - 1) / EPB;    // 196 for E=1.6M (k_tile supports <= FBMAX)

    char* ws = (char*)d_ws;
    __half* xph = (__half*)ws;   ws += (size_t)N * 128 * 2;          // 25.6 MB
    float* l    = (float*)ws;    ws += (size_t)N * 4 * 4;
    float* r    = (float*)ws;    ws += (size_t)N * 4 * 4;
    int* starts = (int*)ws;      ws += (size_t)FB * (NB + 1) * 4;    // 1.23 MB
    unsigned int* slab = (unsigned int*)ws; ws += (size_t)FB * EPB * 4; // 6.42 MB

    float* out = (float*)d_out;
    int GB = (N + 127) / 128;
    int TOT = FB + GB;
    int S = TOT / FB; if (S < 1) S = 1;   // fill role every S-th block

    k_fg<<<TOT, 512, 0, stream>>>(x, W, attl, attr, ei, xph, l, r, slab, starts,
                                  N, E, NB, FB, S);
    k_tile<<<NB, 512, 0, stream>>>(starts, slab, l, r, xph, bias, out, N, NB, FB);
}